// Round 12
// baseline (5713.936 us; speedup 1.0000x reference)
//
#include <hip/hip_runtime.h>
#include <hip/hip_bf16.h>

// ---------------------------------------------------------------------------
// Encoder: emb gather -> LSTM0 -> LSTM1 -> BatchNorm(inference)
// B=64, T=128, D=256, H=1024, 4H=4096, BT=8192 rows.
//
// Round-12: DATA-AS-FLAG decoupled recurrence.
//  - r6-r11 lesson: each device-scope hop (store-visible / flag / observe)
//    costs ~1us; r11's flag path had 4 hops -> 11us/step. Fix: hall slots
//    are WRITE-ONCE, so no barrier is needed at all — readers poll their own
//    MFMA A-operands directly. Slots pre-filled with bf16-NaN sentinel
//    0xFFC1 (h=sigma*tanh is always finite -> no collision). 8B agent-atomic
//    granules -> no tearing. Writers: 2 agent u64 stores per chunk, NO
//    drain, NO flag, NO barrier; they run ahead immediately.
//  - Wave-per-chain (r11): 128 WGs x 256thr; WG = 32-pc slice; wave w =
//    chain w (16 rows) full K=1024; zero intra-WG barriers (lgkmcnt only).
//    4 chains overlap their comm latency on the CU's 4 SIMDs.
//  - U slice 64KB LDS (16x16 frag order); A polled into regs; XW cached.
//  - c-state layer handoff via agent atomics (no same-CU L2 assumption).
//  - Sentinel pre-fill runs inside kernel_launch every call (graph-replay
//    safe, deterministic). hall0: 129 slots; hall1: 128 slots.
// ---------------------------------------------------------------------------

typedef __attribute__((ext_vector_type(8))) short short8;
typedef __attribute__((ext_vector_type(4))) short short4v;
typedef __attribute__((ext_vector_type(4))) float f32x4;
typedef unsigned short ushort_t;
typedef unsigned long long u64;

#define SENT16 ((unsigned short)0xFFC1u)
#define SENT64 0xFFC1FFC1FFC1FFC1ULL

__device__ __forceinline__ void lgkm0() {
  asm volatile("s_waitcnt lgkmcnt(0)" ::: "memory");
}

__device__ __forceinline__ ushort_t f2b(float f) {
  __hip_bfloat16 h = __float2bfloat16(f);
  return *reinterpret_cast<ushort_t*>(&h);
}
__device__ __forceinline__ float b2f(ushort_t u) {
  unsigned int x = ((unsigned int)u) << 16;
  return __builtin_bit_cast(float, x);
}
__device__ __forceinline__ float fsigmoid(float x) {
  return 1.f / (1.f + __expf(-x));
}
__device__ __forceinline__ float ftanh(float x) {
  return 1.f - 2.f / (__expf(2.f * x) + 1.f);
}

__device__ __forceinline__ void gload_lds16(const ushort_t* g, ushort_t* l) {
  __builtin_amdgcn_global_load_lds(
      (const __attribute__((address_space(1))) unsigned int*)g,
      (__attribute__((address_space(3))) unsigned int*)l, 16, 0, 0);
}

__device__ __forceinline__ u64 aload(const u64* p) {
  return __hip_atomic_load(p, __ATOMIC_RELAXED, __HIP_MEMORY_SCOPE_AGENT);
}
__device__ __forceinline__ void astore(u64* p, u64 v) {
  __hip_atomic_store(p, v, __ATOMIC_RELAXED, __HIP_MEMORY_SCOPE_AGENT);
}

// ---- convert W [K][4096] f32 -> [pc][k] bf16 (GEMM B-operand) -------------
__global__ __launch_bounds__(256) void k_convert(
    const float* __restrict__ src, ushort_t* __restrict__ dst, int kshift) {
  size_t tid = (size_t)blockIdx.x * 256 + threadIdx.x;  // = k*4096 + c
  int k = (int)(tid >> 12);
  int c = (int)(tid & 4095);
  int pc = ((c & 1023) << 2) | (c >> 10);
  dst[((size_t)pc << kshift) + k] = f2b(src[tid]);
}

// ---- convert U [1024][4096] f32 -> per-slice(32pc) 16x16 frag order -------
// cid = ((ws*2+tp)*32+ks)*64+l: pc = ws*32+tp*16+(l&15), k = ks*32+(l>>4)*8+e
__global__ __launch_bounds__(256) void k_convert_u(
    const float* __restrict__ src, ushort_t* __restrict__ dst) {
  int cid = blockIdx.x * 256 + threadIdx.x;   // 524288 chunks
  int l = cid & 63;
  int ks = (cid >> 6) & 31;
  int tp = (cid >> 11) & 1;
  int ws = cid >> 12;                          // 0..127
  int pc = ws * 32 + tp * 16 + (l & 15);
  int c = ((pc & 3) << 10) | (pc >> 2);
  int k0 = ks * 32 + (l >> 4) * 8;
  short8 v;
#pragma unroll
  for (int e = 0; e < 8; ++e)
    v[e] = (short)f2b(src[(size_t)(k0 + e) * 4096 + c]);
  *(short8*)(dst + (size_t)cid * 8) = v;
}

// ---- permute biases -------------------------------------------------------
__global__ __launch_bounds__(256) void k_bias(
    const float* __restrict__ b0, const float* __restrict__ b1,
    float* __restrict__ bp0, float* __restrict__ bp1) {
  int pc = blockIdx.x * 256 + threadIdx.x;
  int c = ((pc & 3) << 10) | (pc >> 2);
  bp0[pc] = b0[c];
  bp1[pc] = b1[c];
}

// ---- embedding gather: plain row-major Xef[8192][256] ---------------------
__global__ __launch_bounds__(256) void k_gather(
    const int* __restrict__ tokens, const float* __restrict__ emb,
    ushort_t* __restrict__ Xef) {
  int row = blockIdx.x;            // row = t*64 + b
  int t = row >> 6, b = row & 63;
  int tok = tokens[b * 128 + t];
  int d = threadIdx.x;
  Xef[(size_t)row * 256 + d] = f2b(emb[(size_t)tok * 256 + d]);
}

// ---- state init: h0 -> hall0 slot0 (agent); c0 -> c_st (agent) ------------
__global__ __launch_bounds__(256) void k_init(
    const float* __restrict__ h0, const float* __restrict__ c0,
    ushort_t* __restrict__ hall0, unsigned* __restrict__ c_st) {
  int tid = blockIdx.x * 256 + threadIdx.x;   // 65536
  __hip_atomic_store(c_st + tid, __builtin_bit_cast(unsigned, c0[tid]),
                     __ATOMIC_RELAXED, __HIP_MEMORY_SCOPE_AGENT);
  if (tid < 16384) {   // 16384 u64 granules of 4 bf16
    int base = tid * 4;
    u64 q = 0;
#pragma unroll
    for (int e = 0; e < 4; ++e)
      q |= (u64)f2b(h0[base + e]) << (16 * e);
    astore((u64*)hall0 + tid, q);
  }
}

// ---- sentinel pre-fill: hall0 slots 1..128 + hall1 slots 0..127 -----------
__global__ __launch_bounds__(256) void k_nanfill(
    ushort_t* __restrict__ hall0, ushort_t* __restrict__ hall1) {
  // 2 x 128 slots x 16384 u64 = 4,194,304 u64
  int tid = blockIdx.x * 256 + threadIdx.x;   // 524288 threads
  u64* r0 = (u64*)(hall0 + 65536);            // slots 1..128
  u64* r1 = (u64*)hall1;
#pragma unroll
  for (int i = 0; i < 4; ++i) {
    astore(r0 + (size_t)tid * 4 + i, SENT64);
    astore(r1 + (size_t)tid * 4 + i, SENT64);
  }
}

// ---- GEMM: C[8192][4096] = A[8192][K] * BT[4096][K]^T ---------------------
template <int NKS, int LAY>
__global__ __launch_bounds__(256) void k_gemm(
    const ushort_t* __restrict__ Af, const ushort_t* __restrict__ BT,
    ushort_t* __restrict__ C) {
  const int K = NKS * 16;
  const int xcd = blockIdx.x & 7, loc = blockIdx.x >> 3;
  const int wgM = xcd * 8 + (loc & 7);
  const int wgN = loc >> 3;
  const int tid = threadIdx.x;
  const int l = tid & 63;
  const int wv = tid >> 6;
  const int wvM = wv & 1, wvN = wv >> 1;

  __shared__ __align__(16) ushort_t Alds[4096];
  __shared__ __align__(16) ushort_t Blds[4096];

  const int m0 = wgM * 128, n0 = wgN * 128;
  f32x4 acc[4][4] = {};

  for (int k0 = 0; k0 < K; k0 += 32) {
    __syncthreads();
#pragma unroll
    for (int jj = 0; jj < 2; ++jj) {
      int c = jj * 256 + tid;
      int kc = c >> 7, r = c & 127;
      int R = m0 + r;
      int kcg = (k0 >> 3) + kc;
      const ushort_t* asrc =
          (LAY == 0) ? (Af + (size_t)R * 256 + kcg * 8)
                     : (Af + (size_t)(R >> 6) * 65536 + (R & 63) * 1024 + kcg * 8);
      gload_lds16(asrc, (ushort_t*)&Alds[(size_t)(jj * 256 + (tid & ~63)) * 8]);
      gload_lds16(BT + (size_t)(n0 + r) * K + k0 + kc * 8,
                  (ushort_t*)&Blds[(size_t)(jj * 256 + (tid & ~63)) * 8]);
    }
    __syncthreads();

    short8 af[4], bf[4];
#pragma unroll
    for (int mt = 0; mt < 4; ++mt)
      af[mt] = *(const short8*)&Alds[((l >> 4) * 128 + wvM * 64 + mt * 16 + (l & 15)) * 8];
#pragma unroll
    for (int nt = 0; nt < 4; ++nt)
      bf[nt] = *(const short8*)&Blds[((l >> 4) * 128 + wvN * 64 + nt * 16 + (l & 15)) * 8];
#pragma unroll
    for (int mt = 0; mt < 4; ++mt)
#pragma unroll
      for (int nt = 0; nt < 4; ++nt)
        acc[mt][nt] =
            __builtin_amdgcn_mfma_f32_16x16x32_bf16(af[mt], bf[nt], acc[mt][nt], 0, 0, 0);
  }

  const int rr0 = wgM * 128 + wvM * 64 + (l >> 4) * 4;
  const int cc0 = wgN * 128 + wvN * 64 + (l & 15);
#pragma unroll
  for (int mt = 0; mt < 4; ++mt)
#pragma unroll
    for (int nt = 0; nt < 4; ++nt)
#pragma unroll
      for (int r = 0; r < 4; ++r)
        C[(size_t)(rr0 + mt * 16 + r) * 4096 + cc0 + nt * 16] =
            f2b(acc[mt][nt][r]);
}

// ---- persistent LSTM layer, wave-per-chain + data-as-flag -----------------
// <<<128,256>>>. WG ws: pc [ws*32,+32) (j [ws*8,+8)). Wave w = chain w:
// rows [w*16,+16), full K=1024. Readers poll A-operand u64 granules for
// != sentinel; writers store h agent-atomically and proceed (no sync ops).
template <int LAYER>
__global__ __launch_bounds__(256, 1) void k_pers(
    const ushort_t* __restrict__ Uf,    // frag order (k_convert_u)
    const ushort_t* __restrict__ XW,    // [8192][4096] bf16 row-major
    const float* __restrict__ bp,       // [4096] permuted bias
    const ushort_t* __restrict__ h0s,   // initial-h slot (valid data)
    const ushort_t* __restrict__ hall_r,// this layer's slot array (reads)
    ushort_t* __restrict__ hall_w,      // this layer's slot array (writes)
    unsigned* __restrict__ c_st,        // [64][1024] f32 bits (agent)
    float* __restrict__ outp,           // L1: d_out
    const float* __restrict__ gamma, const float* __restrict__ beta,
    const float* __restrict__ mean, const float* __restrict__ var) {
  const int ws = blockIdx.x;            // 0..127
  const int tid = threadIdx.x;
  const int l = tid & 63;
  const int w = tid >> 6;               // wave = chain

  __shared__ __align__(16) ushort_t Ulds[2][32][512];  // 64 KB U slice
  __shared__ float zrel[4][2][16][20];                 // padded, aligned
  __shared__ ushort_t hrel[4][16][8];

  // ---- stage U slice (4096 x 16B) ----
  {
    const ushort_t* src = Uf + (size_t)ws * 32768;
    for (int i = tid; i < 4096; i += 256)
      *(short8*)((ushort_t*)Ulds + (size_t)i * 8) =
          *(const short8*)(src + (size_t)i * 8);
  }

  // ---- per-lane constants ----
  const int b_loc = l & 15;
  const int b = w * 16 + b_loc;
  const int kg = l >> 4;                // 0..3
  float creg[2], scl[2], sft[2];
  f32x4 biasv[2];
#pragma unroll
  for (int p = 0; p < 2; ++p) {
    const int jo = kg + 4 * p;
    const int j = ws * 8 + jo;
    creg[p] = __builtin_bit_cast(
        float, __hip_atomic_load(c_st + b * 1024 + j, __ATOMIC_RELAXED,
                                 __HIP_MEMORY_SCOPE_AGENT));
    biasv[p] = *(const f32x4*)(bp + ws * 32 + jo * 4);
    if (LAYER == 1) {
      float inv = rsqrtf(var[j] + 1e-3f);
      scl[p] = inv * gamma[j];
      sft[p] = beta[j] - mean[j] * scl[p];
    }
  }

  __syncthreads();   // Ulds visible (only barrier in the kernel)

#pragma unroll 1
  for (int t = 0; t < 128; ++t) {
    const ushort_t* hin =
        (t == 0) ? h0s : (hall_r + (size_t)(LAYER == 0 ? t : t - 1) * 65536);
    ushort_t* hout = hall_w + (size_t)(LAYER == 0 ? t + 1 : t) * 65536;

    // ---- A: poll 64 u64 granules (32 chunks) until non-sentinel ----
    const u64* ab64 = (const u64*)(hin + (size_t)b * 1024 + kg * 8);
    u64 arq[32][2];
    const bool nocheck = (t == 0);
    for (;;) {
      bool ok = true;
#pragma unroll
      for (int ks = 0; ks < 32; ++ks) {
        u64 q0 = aload(ab64 + ks * 8 + 0);
        u64 q1 = aload(ab64 + ks * 8 + 1);
        arq[ks][0] = q0;
        arq[ks][1] = q1;
        ok &= ((unsigned short)q0 != SENT16);
        ok &= ((unsigned short)q1 != SENT16);
      }
      if (nocheck || __all(ok)) break;
      __builtin_amdgcn_s_sleep(8);
    }

    // ---- XW for this step (cached; overlaps) ----
    short4v xw[2];
#pragma unroll
    for (int p = 0; p < 2; ++p)
      xw[p] = *(const short4v*)(
          XW + ((size_t)(t * 64 + b) << 12) + ws * 32 + (kg + 4 * p) * 4);

    // ---- 64 MFMAs: 2 pc-tiles x 32 ks (A reg, B LDS) ----
    f32x4 acc[2][2] = {};
#pragma unroll
    for (int ks = 0; ks < 32; ++ks) {
      union { u64 q[2]; short8 s; } ua;
      ua.q[0] = arq[ks][0];
      ua.q[1] = arq[ks][1];
      short8 a = ua.s;
      short8 q0 = *(const short8*)&Ulds[0][ks][l * 8];
      acc[0][ks & 1] =
          __builtin_amdgcn_mfma_f32_16x16x32_bf16(a, q0, acc[0][ks & 1], 0, 0, 0);
      short8 q1 = *(const short8*)&Ulds[1][ks][l * 8];
      acc[1][ks & 1] =
          __builtin_amdgcn_mfma_f32_16x16x32_bf16(a, q1, acc[1][ks & 1], 0, 0, 0);
    }

    // ---- z relay via wave-private LDS (no barrier) ----
#pragma unroll
    for (int tp = 0; tp < 2; ++tp)
#pragma unroll
      for (int r = 0; r < 4; ++r)
        zrel[w][tp][kg * 4 + r][b_loc] = acc[tp][0][r] + acc[tp][1][r];
    lgkm0();

    // ---- epilogue: 2 (b,j) pairs per lane ----
    float hn[2];
#pragma unroll
    for (int p = 0; p < 2; ++p) {
      const int jo = kg + 4 * p;
      f32x4 zv = *(const f32x4*)&zrel[w][jo >> 2][b_loc][(jo & 3) * 4];
      float zi = zv[0] + b2f((ushort_t)xw[p][0]) + biasv[p][0];
      float zf = zv[1] + b2f((ushort_t)xw[p][1]) + biasv[p][1];
      float zg = zv[2] + b2f((ushort_t)xw[p][2]) + biasv[p][2];
      float zo = zv[3] + b2f((ushort_t)xw[p][3]) + biasv[p][3];
      float ii = fsigmoid(zi), ff = fsigmoid(zf), oo = fsigmoid(zo);
      float gg = ftanh(zg);
      creg[p] = ff * creg[p] + ii * gg;
      hn[p] = oo * ftanh(creg[p]);
      hrel[w][b_loc][jo] = f2b(hn[p]);
      if (LAYER == 1) {
        const int j = ws * 8 + jo;
        outp[((size_t)b * 128 + t) * 1024 + j] = hn[p] * scl[p] + sft[p];
        if (t == 127) {
          outp[8388608 + b * 1024 + j] = hn[p];
          outp[8454144 + b * 1024 + j] = creg[p];
        }
      } else if (t == 127) {
        __hip_atomic_store(c_st + b * 1024 + ws * 8 + jo,
                           __builtin_bit_cast(unsigned, creg[p]),
                           __ATOMIC_RELAXED, __HIP_MEMORY_SCOPE_AGENT);
      }
    }
    lgkm0();

    // ---- h out: lanes 0..15, two agent u64 stores; NO drain, NO flag ----
    if (l < 16) {
      union { short8 s; u64 q[2]; } cv;
      cv.s = *(const short8*)&hrel[w][l][0];
      u64* dst = (u64*)(hout + (size_t)(w * 16 + l) * 1024 + ws * 8);
      astore(dst + 0, cv.q[0]);
      astore(dst + 1, cv.q[1]);
    }
  }
}

extern "C" void kernel_launch(void* const* d_in, const int* in_sizes, int n_in,
                              void* d_out, int out_size, void* d_ws,
                              size_t ws_size, hipStream_t stream) {
  const int* tokens = (const int*)d_in[0];
  const float* h0 = (const float*)d_in[1];
  const float* c0 = (const float*)d_in[2];
  const float* emb = (const float*)d_in[3];
  const float* W0 = (const float*)d_in[4];
  const float* U0 = (const float*)d_in[5];
  const float* b0 = (const float*)d_in[6];
  const float* W1 = (const float*)d_in[7];
  const float* U1 = (const float*)d_in[8];
  const float* b1 = (const float*)d_in[9];
  const float* gammap = (const float*)d_in[10];
  const float* betap = (const float*)d_in[11];
  const float* mmean = (const float*)d_in[12];
  const float* mvar = (const float*)d_in[13];

  char* ws = (char*)d_ws;
  ushort_t* Uc0 = (ushort_t*)(ws + 0);             //  8 MB frag U0
  ushort_t* Uc1 = (ushort_t*)(ws + 8388608);       //  8 MB frag U1
  ushort_t* W0f = (ushort_t*)(ws + 16777216);      //  2 MB [pc][256]
  ushort_t* W1f = (ushort_t*)(ws + 18874368);      //  8 MB [pc][1024]
  float* bp0 = (float*)(ws + 27262976);            // 16 KB
  float* bp1 = (float*)(ws + 27279360);            // 16 KB
  ushort_t* Xef = (ushort_t*)(ws + 27295744);      //  4 MB [8192][256]
  ushort_t* XW = (ushort_t*)(ws + 31490048);       // 64 MB [8192][4096]
  ushort_t* hall0 = (ushort_t*)(ws + 98598912);    // 16.5 MB: 129 slots
  ushort_t* hall1 = (ushort_t*)(ws + 115507200);   // 16 MB: 128 slots
  unsigned* c_st = (unsigned*)(ws + 132284416);    // 256 KB (f32 bits)

  k_convert_u<<<2048, 256, 0, stream>>>(U0, Uc0);
  k_convert_u<<<2048, 256, 0, stream>>>(U1, Uc1);
  k_convert<<<4096, 256, 0, stream>>>(W0, W0f, 8);
  k_convert<<<16384, 256, 0, stream>>>(W1, W1f, 10);
  k_bias<<<16, 256, 0, stream>>>(b0, b1, bp0, bp1);
  k_gather<<<8192, 256, 0, stream>>>(tokens, emb, Xef);
  k_init<<<256, 256, 0, stream>>>(h0, c0, hall0, c_st);
  k_nanfill<<<2048, 256, 0, stream>>>(hall0, hall1);

  float* outp = (float*)d_out;

  // ---- layer 0 (reads hall0 slots, writes hall0 slots 1..128) ----
  k_gemm<16, 0><<<2048, 256, 0, stream>>>(Xef, W0f, XW);
  k_pers<0><<<128, 256, 0, stream>>>(Uc0, XW, bp0, hall0, hall0, hall0, c_st,
                                     nullptr, nullptr, nullptr, nullptr,
                                     nullptr);

  // ---- layer 1 (GEMM A = hall0 slots 1..128; h0 = hall0 slot 128) ----
  k_gemm<64, 1><<<2048, 256, 0, stream>>>(hall0 + 65536, W1f, XW);
  k_pers<1><<<128, 256, 0, stream>>>(Uc1, XW, bp1, hall0 + (size_t)128 * 65536,
                                     hall1, hall1, c_st, outp, gammap, betap,
                                     mmean, mvar);
}

// Round 13
// 3460.869 us; speedup vs baseline: 1.6510x; 1.6510x over previous
//
#include <hip/hip_runtime.h>
#include <hip/hip_bf16.h>

// ---------------------------------------------------------------------------
// Encoder: emb gather -> LSTM0 -> LSTM1 -> BatchNorm(inference)
// B=64, T=128, D=256, H=1024, 4H=4096, BT=8192 rows.
//
// Round-13: DECOUPLED-CHAIN persistent recurrence.
//  - Measured r6-r12: every 128-WG lockstep topology = 6.3-6.5us/step; model:
//    per-WG step ~4us + jitter, lockstep pays max-over-128 each step. Fix:
//    rows are recurrence-independent -> 4 chains x 16 rows, each chain a
//    private 64-WG sub-grid with its own counter lines; chains drift freely.
//  - Wave-autonomous steps: wave = one 16-pc tile x full K=1024 (32 MFMAs,
//    16x16x32) -> no cross-wave reduce, ZERO intra-WG s_barriers in the loop
//    (wave-private zrel/hrel + lgkmcnt only). Per-wave arrive (1 RMW) and
//    per-line poll (lanes 0..7 + __all).
//  - Proven r10 combo kept: agent-atomic h-stores + normal cached A-loads
//    (per-step-unique slots) + narrow counter polling (r12 lesson: never
//    poll bulk data at device scope). outp/BN stores in post-arrive window.
//  - XW precomputed by GEMMs; layers strictly sequential (L1 init state =
//    L0 FINAL state per reference -> no layer pipelining possible).
// ---------------------------------------------------------------------------

typedef __attribute__((ext_vector_type(8))) short short8;
typedef __attribute__((ext_vector_type(4))) short short4v;
typedef __attribute__((ext_vector_type(4))) float f32x4;
typedef unsigned short ushort_t;
typedef unsigned long long u64;

__device__ __forceinline__ void lgkm0() {
  asm volatile("s_waitcnt lgkmcnt(0)" ::: "memory");
}

__device__ __forceinline__ ushort_t f2b(float f) {
  __hip_bfloat16 h = __float2bfloat16(f);
  return *reinterpret_cast<ushort_t*>(&h);
}
__device__ __forceinline__ float b2f(ushort_t u) {
  unsigned int x = ((unsigned int)u) << 16;
  return __builtin_bit_cast(float, x);
}
__device__ __forceinline__ float fsigmoid(float x) {
  return 1.f / (1.f + __expf(-x));
}
__device__ __forceinline__ float ftanh(float x) {
  return 1.f - 2.f / (__expf(2.f * x) + 1.f);
}

__device__ __forceinline__ void gload_lds16(const ushort_t* g, ushort_t* l) {
  __builtin_amdgcn_global_load_lds(
      (const __attribute__((address_space(1))) unsigned int*)g,
      (__attribute__((address_space(3))) unsigned int*)l, 16, 0, 0);
}

// ---- convert W [K][4096] f32 -> [pc][k] bf16 (GEMM B-operand) -------------
__global__ __launch_bounds__(256) void k_convert(
    const float* __restrict__ src, ushort_t* __restrict__ dst, int kshift) {
  size_t tid = (size_t)blockIdx.x * 256 + threadIdx.x;  // = k*4096 + c
  int k = (int)(tid >> 12);
  int c = (int)(tid & 4095);
  int pc = ((c & 1023) << 2) | (c >> 10);
  dst[((size_t)pc << kshift) + k] = f2b(src[tid]);
}

// ---- convert U [1024][4096] f32 -> per-slice(64pc) 16x16 frag order -------
// cid = ((ws*4+nt)*32+ks)*64+l:
//   pc = ws*64 + nt*16 + (l&15), k = ks*32 + (l>>4)*8 + e
__global__ __launch_bounds__(256) void k_convert_u(
    const float* __restrict__ src, ushort_t* __restrict__ dst) {
  int cid = blockIdx.x * 256 + threadIdx.x;   // 524288 chunks
  int l = cid & 63;
  int ks = (cid >> 6) & 31;
  int nt = (cid >> 11) & 3;
  int ws = cid >> 13;                          // 0..63
  int pc = ws * 64 + nt * 16 + (l & 15);
  int c = ((pc & 3) << 10) | (pc >> 2);
  int k0 = ks * 32 + (l >> 4) * 8;
  short8 v;
#pragma unroll
  for (int e = 0; e < 8; ++e)
    v[e] = (short)f2b(src[(size_t)(k0 + e) * 4096 + c]);
  *(short8*)(dst + (size_t)cid * 8) = v;
}

// ---- permute biases -------------------------------------------------------
__global__ __launch_bounds__(256) void k_bias(
    const float* __restrict__ b0, const float* __restrict__ b1,
    float* __restrict__ bp0, float* __restrict__ bp1) {
  int pc = blockIdx.x * 256 + threadIdx.x;
  int c = ((pc & 3) << 10) | (pc >> 2);
  bp0[pc] = b0[c];
  bp1[pc] = b1[c];
}

// ---- embedding gather: plain row-major Xef[8192][256] ---------------------
__global__ __launch_bounds__(256) void k_gather(
    const int* __restrict__ tokens, const float* __restrict__ emb,
    ushort_t* __restrict__ Xef) {
  int row = blockIdx.x;            // row = t*64 + b
  int t = row >> 6, b = row & 63;
  int tok = tokens[b * 128 + t];
  int d = threadIdx.x;
  Xef[(size_t)row * 256 + d] = f2b(emb[(size_t)tok * 256 + d]);
}

// ---- state init: h0 -> hall0 slot0; c0 -> c_st; zero counters -------------
__global__ __launch_bounds__(256) void k_init(
    const float* __restrict__ h0, const float* __restrict__ c0,
    ushort_t* __restrict__ hall0, float* __restrict__ c_st,
    unsigned* __restrict__ bars) {
  int tid = blockIdx.x * 256 + threadIdx.x;
  c_st[tid] = c0[tid];
  hall0[tid] = f2b(h0[tid]);
  if (tid < 2048) bars[tid] = 0;
}

// ---- GEMM: C[8192][4096] = A[8192][K] * BT[4096][K]^T ---------------------
// A plain row-major (LAY=0: Xef; LAY=1: hall0 slots 1..128). 128x128 tile,
// global_load_lds staging, XCD-blocked (8 wgM inner, wgN outer).
template <int NKS, int LAY>
__global__ __launch_bounds__(256) void k_gemm(
    const ushort_t* __restrict__ Af, const ushort_t* __restrict__ BT,
    ushort_t* __restrict__ C) {
  const int K = NKS * 16;
  const int xcd = blockIdx.x & 7, loc = blockIdx.x >> 3;
  const int wgM = xcd * 8 + (loc & 7);
  const int wgN = loc >> 3;
  const int tid = threadIdx.x;
  const int l = tid & 63;
  const int wv = tid >> 6;
  const int wvM = wv & 1, wvN = wv >> 1;

  __shared__ __align__(16) ushort_t Alds[4096];
  __shared__ __align__(16) ushort_t Blds[4096];

  const int m0 = wgM * 128, n0 = wgN * 128;
  f32x4 acc[4][4] = {};

  for (int k0 = 0; k0 < K; k0 += 32) {
    __syncthreads();
#pragma unroll
    for (int jj = 0; jj < 2; ++jj) {
      int c = jj * 256 + tid;
      int kc = c >> 7, r = c & 127;
      int R = m0 + r;
      int kcg = (k0 >> 3) + kc;
      const ushort_t* asrc =
          (LAY == 0) ? (Af + (size_t)R * 256 + kcg * 8)
                     : (Af + (size_t)(R >> 6) * 65536 + (R & 63) * 1024 + kcg * 8);
      gload_lds16(asrc, (ushort_t*)&Alds[(size_t)(jj * 256 + (tid & ~63)) * 8]);
      gload_lds16(BT + (size_t)(n0 + r) * K + k0 + kc * 8,
                  (ushort_t*)&Blds[(size_t)(jj * 256 + (tid & ~63)) * 8]);
    }
    __syncthreads();

    short8 af[4], bf[4];
#pragma unroll
    for (int mt = 0; mt < 4; ++mt)
      af[mt] = *(const short8*)&Alds[((l >> 4) * 128 + wvM * 64 + mt * 16 + (l & 15)) * 8];
#pragma unroll
    for (int nt = 0; nt < 4; ++nt)
      bf[nt] = *(const short8*)&Blds[((l >> 4) * 128 + wvN * 64 + nt * 16 + (l & 15)) * 8];
#pragma unroll
    for (int mt = 0; mt < 4; ++mt)
#pragma unroll
      for (int nt = 0; nt < 4; ++nt)
        acc[mt][nt] =
            __builtin_amdgcn_mfma_f32_16x16x32_bf16(af[mt], bf[nt], acc[mt][nt], 0, 0, 0);
  }

  const int rr0 = wgM * 128 + wvM * 64 + (l >> 4) * 4;
  const int cc0 = wgN * 128 + wvN * 64 + (l & 15);
#pragma unroll
  for (int mt = 0; mt < 4; ++mt)
#pragma unroll
    for (int nt = 0; nt < 4; ++nt)
#pragma unroll
      for (int r = 0; r < 4; ++r)
        C[(size_t)(rr0 + mt * 16 + r) * 4096 + cc0 + nt * 16] =
            f2b(acc[mt][nt][r]);
}

// ---- persistent LSTM layer, decoupled chains, <<<256,256>>> ---------------
// bid: chain = bid&3 (16 rows), ws = bid>>2 (64-pc slice, 16 j).
// Wave nt = 16-pc tile over FULL K=1024: 32x 16x16x32 MFMA (A reg, B LDS).
// No intra-WG barriers in the loop. Per-chain counter lines (8 per chain).
template <int LAYER>
__global__ __launch_bounds__(256, 1) void k_pers(
    const ushort_t* __restrict__ Uf,    // frag order (k_convert_u)
    const ushort_t* __restrict__ XW,    // [8192][4096] bf16 row-major
    const float* __restrict__ bp,       // [4096] permuted bias
    const ushort_t* __restrict__ h0s,   // initial-h slot (row-major)
    const ushort_t* __restrict__ hall_r,// read slots base
    ushort_t* __restrict__ hall_w,      // write slots base
    float* __restrict__ c_st,           // [64][1024] f32
    float* __restrict__ outp,           // L1: d_out
    const float* __restrict__ gamma, const float* __restrict__ beta,
    const float* __restrict__ mean, const float* __restrict__ var,
    unsigned* __restrict__ bar) {       // this layer's 32 lines (x16 stride)
  const int bid = blockIdx.x;
  const int chain = bid & 3;
  const int ws = bid >> 2;              // 0..63
  const int tid = threadIdx.x;
  const int l = tid & 63;
  const int nt = tid >> 6;              // wave = pc-tile

  __shared__ __align__(16) ushort_t Ulds[4][32][512];  // 128 KB
  __shared__ float zrel[4][16][20];                    // wave-private z
  __shared__ ushort_t hrel[4][16][4];                  // wave-private h

  // ---- stage U slice (8192 x 16B) ----
  {
    const ushort_t* src = Uf + (size_t)ws * 65536;
    for (int i = tid; i < 8192; i += 256)
      *(short8*)((ushort_t*)Ulds + (size_t)i * 8) =
          *(const short8*)(src + (size_t)i * 8);
  }

  // ---- per-lane constants ----
  const int row_e = l & 15;                    // epilogue row (local)
  const int rowg_e = chain * 16 + row_e;       // global batch row
  const int jq = l >> 4;                       // 0..3
  const int j = ws * 16 + nt * 4 + jq;         // global j
  float creg = c_st[rowg_e * 1024 + j];
  const f32x4 bias_v = *(const f32x4*)(bp + ws * 64 + nt * 16 + jq * 4);
  float scl = 0.f, sft = 0.f;
  if (LAYER == 1) {
    float inv = rsqrtf(var[j] + 1e-3f);
    scl = inv * gamma[j];
    sft = beta[j] - mean[j] * scl;
  }
  const int rowA = chain * 16 + (l & 15);      // MFMA A row (same formula)
  unsigned* myline = bar + (chain * 8 + (ws & 7)) * 16;

  __syncthreads();   // Ulds visible; ONLY barrier in the kernel

#pragma unroll 1
  for (int t = 0; t < 128; ++t) {
    // ---- poll chain counters: all 8 lines >= 32*t (t>0) ----
    if (t > 0) {
      const unsigned tgt = 32u * (unsigned)t;
      for (;;) {
        bool ok = true;
        if (l < 8)
          ok = __hip_atomic_load(bar + (chain * 8 + l) * 16, __ATOMIC_RELAXED,
                                 __HIP_MEMORY_SCOPE_AGENT) >= tgt;
        if (__all(ok)) break;
        __builtin_amdgcn_s_sleep(2);
      }
      asm volatile("" ::: "memory");   // compiler fence: loads stay after poll
    }

    const ushort_t* hin =
        (LAYER == 0) ? (hall_r + (size_t)t * 65536)
                     : ((t == 0) ? h0s : (hall_r + (size_t)(t - 1) * 65536));
    ushort_t* hout = hall_w + (size_t)(LAYER == 0 ? t + 1 : t) * 65536;

    // ---- XW for this step (cached) ----
    short4v xw = *(const short4v*)(
        XW + ((size_t)(t * 64 + rowg_e) << 12) + ws * 64 + nt * 16 + jq * 4);

    // ---- A: 32 back-to-back 16B cached loads (rows of my chain) ----
    const ushort_t* ab = hin + (size_t)rowA * 1024 + (l >> 4) * 8;
    short8 ar[32];
#pragma unroll
    for (int ks = 0; ks < 32; ++ks)
      ar[ks] = *(const short8*)(ab + ks * 32);

    // ---- 32 MFMAs over K=1024 (A reg, B from LDS, 4 chains) ----
    f32x4 acc0 = {}, acc1 = {}, acc2 = {}, acc3 = {};
#pragma unroll
    for (int ks = 0; ks < 32; ks += 4) {
      short8 b0 = *(const short8*)&Ulds[nt][ks + 0][l * 8];
      short8 b1 = *(const short8*)&Ulds[nt][ks + 1][l * 8];
      short8 b2 = *(const short8*)&Ulds[nt][ks + 2][l * 8];
      short8 b3 = *(const short8*)&Ulds[nt][ks + 3][l * 8];
      acc0 = __builtin_amdgcn_mfma_f32_16x16x32_bf16(ar[ks + 0], b0, acc0, 0, 0, 0);
      acc1 = __builtin_amdgcn_mfma_f32_16x16x32_bf16(ar[ks + 1], b1, acc1, 0, 0, 0);
      acc2 = __builtin_amdgcn_mfma_f32_16x16x32_bf16(ar[ks + 2], b2, acc2, 0, 0, 0);
      acc3 = __builtin_amdgcn_mfma_f32_16x16x32_bf16(ar[ks + 3], b3, acc3, 0, 0, 0);
    }
    f32x4 zt = (acc0 + acc1) + (acc2 + acc3);

    // ---- z relay, wave-private (16x16 C layout: row=(l>>4)*4+r, col=l&15)
#pragma unroll
    for (int r = 0; r < 4; ++r)
      zrel[nt][(l >> 4) * 4 + r][l & 15] = zt[r];
    lgkm0();

    // ---- epilogue: lane owns (row_e, j) ----
    f32x4 zv = *(const f32x4*)&zrel[nt][row_e][jq * 4];
    float zi = zv[0] + b2f((ushort_t)xw[0]) + bias_v[0];
    float zf = zv[1] + b2f((ushort_t)xw[1]) + bias_v[1];
    float zg = zv[2] + b2f((ushort_t)xw[2]) + bias_v[2];
    float zo = zv[3] + b2f((ushort_t)xw[3]) + bias_v[3];
    float ii = fsigmoid(zi), ff = fsigmoid(zf), oo = fsigmoid(zo);
    float gg = ftanh(zg);
    creg = ff * creg + ii * gg;
    float hn = oo * ftanh(creg);
    hrel[nt][row_e][jq] = f2b(hn);
    lgkm0();

    // ---- h out: lanes 0..15, one u64 agent store (4 bf16 = my j-quad) ----
    if (l < 16) {
      u64 v = *(const u64*)&hrel[nt][l][0];
      __hip_atomic_store(
          (u64*)(hout + (size_t)(chain * 16 + l) * 1024 + ws * 16 + nt * 4), v,
          __ATOMIC_RELAXED, __HIP_MEMORY_SCOPE_AGENT);
    }

    // ---- drain this wave's stores, arrive on my chain line ----
    asm volatile("s_waitcnt vmcnt(0)" ::: "memory");
    if (l == 0)
      __hip_atomic_fetch_add(myline, 1u, __ATOMIC_RELAXED,
                             __HIP_MEMORY_SCOPE_AGENT);

    // ---- post-arrive window: outp/BN + final state stores ----
    if (LAYER == 1) {
      outp[((size_t)rowg_e * 128 + t) * 1024 + j] = hn * scl + sft;
      if (t == 127) {
        outp[8388608 + rowg_e * 1024 + j] = hn;
        outp[8454144 + rowg_e * 1024 + j] = creg;
      }
    } else if (t == 127) {
      c_st[rowg_e * 1024 + j] = creg;
    }
  }
}

extern "C" void kernel_launch(void* const* d_in, const int* in_sizes, int n_in,
                              void* d_out, int out_size, void* d_ws,
                              size_t ws_size, hipStream_t stream) {
  const int* tokens = (const int*)d_in[0];
  const float* h0 = (const float*)d_in[1];
  const float* c0 = (const float*)d_in[2];
  const float* emb = (const float*)d_in[3];
  const float* W0 = (const float*)d_in[4];
  const float* U0 = (const float*)d_in[5];
  const float* b0 = (const float*)d_in[6];
  const float* W1 = (const float*)d_in[7];
  const float* U1 = (const float*)d_in[8];
  const float* b1 = (const float*)d_in[9];
  const float* gammap = (const float*)d_in[10];
  const float* betap = (const float*)d_in[11];
  const float* mmean = (const float*)d_in[12];
  const float* mvar = (const float*)d_in[13];

  char* ws = (char*)d_ws;
  ushort_t* Uc0 = (ushort_t*)(ws + 0);             //  8 MB frag U0
  ushort_t* Uc1 = (ushort_t*)(ws + 8388608);       //  8 MB frag U1
  ushort_t* W0f = (ushort_t*)(ws + 16777216);      //  2 MB [pc][256]
  ushort_t* W1f = (ushort_t*)(ws + 18874368);      //  8 MB [pc][1024]
  float* bp0 = (float*)(ws + 27262976);            // 16 KB
  float* bp1 = (float*)(ws + 27279360);            // 16 KB
  ushort_t* Xef = (ushort_t*)(ws + 27295744);      //  4 MB [8192][256]
  ushort_t* XW = (ushort_t*)(ws + 31490048);       // 64 MB [8192][4096]
  ushort_t* hall0 = (ushort_t*)(ws + 98598912);    // 16.5 MB: 129 slots
  ushort_t* hall1 = (ushort_t*)(ws + 115507200);   // 16 MB: 128 slots
  float* c_st = (float*)(ws + 132284416);          // 256 KB
  unsigned* bars = (unsigned*)(ws + 132546560);    // 8 KB (2 x 32 lines x 16)

  k_convert_u<<<2048, 256, 0, stream>>>(U0, Uc0);
  k_convert_u<<<2048, 256, 0, stream>>>(U1, Uc1);
  k_convert<<<4096, 256, 0, stream>>>(W0, W0f, 8);
  k_convert<<<16384, 256, 0, stream>>>(W1, W1f, 10);
  k_bias<<<16, 256, 0, stream>>>(b0, b1, bp0, bp1);
  k_gather<<<8192, 256, 0, stream>>>(tokens, emb, Xef);
  k_init<<<256, 256, 0, stream>>>(h0, c0, hall0, c_st, bars);

  float* outp = (float*)d_out;

  // ---- layer 0 (reads hall0[t], writes hall0[t+1]) ----
  k_gemm<16, 0><<<2048, 256, 0, stream>>>(Xef, W0f, XW);
  k_pers<0><<<256, 256, 0, stream>>>(Uc0, XW, bp0, nullptr, hall0, hall0,
                                     c_st, nullptr, nullptr, nullptr, nullptr,
                                     nullptr, bars);

  // ---- layer 1 (GEMM A = hall0 slots 1..128; h init = hall0 slot 128) ----
  k_gemm<64, 1><<<2048, 256, 0, stream>>>(hall0 + 65536, W1f, XW);
  k_pers<1><<<256, 256, 0, stream>>>(Uc1, XW, bp1,
                                     hall0 + (size_t)128 * 65536, hall1, hall1,
                                     c_st, outp, gammap, betap, mmean, mvar,
                                     bars + 512);
}

// Round 14
// 1640.630 us; speedup vs baseline: 3.4828x; 2.1095x over previous
//
#include <hip/hip_runtime.h>
#include <hip/hip_bf16.h>

// ---------------------------------------------------------------------------
// Encoder: emb gather -> LSTM0 -> LSTM1 -> BatchNorm(inference)
// B=64, T=128, D=256, H=1024, 4H=4096, BT=8192 rows.
//
// Round-14: DATA-AS-FLAG v2 (poll your own operands, pipelined).
//  - r6-r13 measured: counter-barrier topologies all pay the serial chain
//    drain->visible->observe->load = 4-5us/step. Merge observe+load: consumers
//    poll their A-operand directly via pipelined 16B sc0sc1 loads + bf16-NaN
//    sentinel (0xFFC1; h=sigma*tanh finite -> collision impossible).
//    Producer: sc0sc1 h-stores, NO drain, NO counter, proceeds immediately.
//  - r12's pathology fixed: (a) 8 pipelined 16B asm loads/lane/round (one
//    latency) vs 64 serialized 8B atomics; (b) disjoint per-wave footprints
//    (wave = K-quarter; 8MB/step chip-wide, L3-resident); (c) VALU sentinel
//    check per 8B granule + __all; (d) sched_barrier(0) after vmcnt.
//  - Geometry: 256 WGs (chain=bid&3: 16 rows; ws=bid>>2: 64 pc = 16 j);
//    4 waves = 4 K-quarters; zls[kq][nt][16][17] reduce (2 barriers/step);
//    epilogue: one (row,j) per thread. U slice 128KB LDS.
//  - t==0 reads are pre-launch-valid slots -> plain cached loads, no poll.
//  - hall slots write-once; sentinel prefill every call (replay-safe).
// ---------------------------------------------------------------------------

typedef __attribute__((ext_vector_type(8))) short short8;
typedef __attribute__((ext_vector_type(4))) short short4v;
typedef __attribute__((ext_vector_type(4))) float f32x4;
typedef unsigned short ushort_t;
typedef unsigned long long u64;

#define SENT16 ((unsigned short)0xFFC1u)
#define SENT64 0xFFC1FFC1FFC1FFC1ULL

#define LOADSC(dst, base, off)                                        \
  asm volatile("global_load_dwordx4 %0, %1, off offset:" #off " sc0 sc1" \
               : "=v"(dst) : "v"(base) : "memory")

__device__ __forceinline__ void lgkm0_bar() {
  asm volatile("s_waitcnt lgkmcnt(0)" ::: "memory");
  __builtin_amdgcn_s_barrier();
}

__device__ __forceinline__ ushort_t f2b(float f) {
  __hip_bfloat16 h = __float2bfloat16(f);
  return *reinterpret_cast<ushort_t*>(&h);
}
__device__ __forceinline__ float b2f(ushort_t u) {
  unsigned int x = ((unsigned int)u) << 16;
  return __builtin_bit_cast(float, x);
}
__device__ __forceinline__ float fsigmoid(float x) {
  return 1.f / (1.f + __expf(-x));
}
__device__ __forceinline__ float ftanh(float x) {
  return 1.f - 2.f / (__expf(2.f * x) + 1.f);
}

__device__ __forceinline__ void store16_sc(ushort_t* p, short8 v) {
  asm volatile("global_store_dwordx4 %0, %1, off sc0 sc1"
               :: "v"(p), "v"(v) : "memory");
}

__device__ __forceinline__ void gload_lds16(const ushort_t* g, ushort_t* l) {
  __builtin_amdgcn_global_load_lds(
      (const __attribute__((address_space(1))) unsigned int*)g,
      (__attribute__((address_space(3))) unsigned int*)l, 16, 0, 0);
}

// ---- convert W [K][4096] f32 -> [pc][k] bf16 (GEMM B-operand) -------------
__global__ __launch_bounds__(256) void k_convert(
    const float* __restrict__ src, ushort_t* __restrict__ dst, int kshift) {
  size_t tid = (size_t)blockIdx.x * 256 + threadIdx.x;  // = k*4096 + c
  int k = (int)(tid >> 12);
  int c = (int)(tid & 4095);
  int pc = ((c & 1023) << 2) | (c >> 10);
  dst[((size_t)pc << kshift) + k] = f2b(src[tid]);
}

// ---- convert U [1024][4096] f32 -> per-slice(64pc) 16x16 frag order -------
// cid = ((ws*4+nt)*32+ks)*64+l:
//   pc = ws*64 + nt*16 + (l&15), k = ks*32 + (l>>4)*8 + e
__global__ __launch_bounds__(256) void k_convert_u(
    const float* __restrict__ src, ushort_t* __restrict__ dst) {
  int cid = blockIdx.x * 256 + threadIdx.x;   // 524288 chunks
  int l = cid & 63;
  int ks = (cid >> 6) & 31;
  int nt = (cid >> 11) & 3;
  int ws = cid >> 13;                          // 0..63
  int pc = ws * 64 + nt * 16 + (l & 15);
  int c = ((pc & 3) << 10) | (pc >> 2);
  int k0 = ks * 32 + (l >> 4) * 8;
  short8 v;
#pragma unroll
  for (int e = 0; e < 8; ++e)
    v[e] = (short)f2b(src[(size_t)(k0 + e) * 4096 + c]);
  *(short8*)(dst + (size_t)cid * 8) = v;
}

// ---- permute biases -------------------------------------------------------
__global__ __launch_bounds__(256) void k_bias(
    const float* __restrict__ b0, const float* __restrict__ b1,
    float* __restrict__ bp0, float* __restrict__ bp1) {
  int pc = blockIdx.x * 256 + threadIdx.x;
  int c = ((pc & 3) << 10) | (pc >> 2);
  bp0[pc] = b0[c];
  bp1[pc] = b1[c];
}

// ---- embedding gather: plain row-major Xef[8192][256] ---------------------
__global__ __launch_bounds__(256) void k_gather(
    const int* __restrict__ tokens, const float* __restrict__ emb,
    ushort_t* __restrict__ Xef) {
  int row = blockIdx.x;            // row = t*64 + b
  int t = row >> 6, b = row & 63;
  int tok = tokens[b * 128 + t];
  int d = threadIdx.x;
  Xef[(size_t)row * 256 + d] = f2b(emb[(size_t)tok * 256 + d]);
}

// ---- state init: h0 -> hall0 slot0; c0 -> c_st ----------------------------
__global__ __launch_bounds__(256) void k_init(
    const float* __restrict__ h0, const float* __restrict__ c0,
    ushort_t* __restrict__ hall0, float* __restrict__ c_st) {
  int tid = blockIdx.x * 256 + threadIdx.x;
  c_st[tid] = c0[tid];
  hall0[tid] = f2b(h0[tid]);
}

// ---- sentinel pre-fill: hall0 slots 1..128 + hall1 slots 0..127 -----------
__global__ __launch_bounds__(256) void k_nanfill(
    ushort_t* __restrict__ hall0, ushort_t* __restrict__ hall1) {
  int tid = blockIdx.x * 256 + threadIdx.x;   // 524288 threads
  u64* r0 = (u64*)(hall0 + 65536);
  u64* r1 = (u64*)hall1;
#pragma unroll
  for (int i = 0; i < 4; ++i) {
    __hip_atomic_store(r0 + (size_t)tid * 4 + i, SENT64, __ATOMIC_RELAXED,
                       __HIP_MEMORY_SCOPE_AGENT);
    __hip_atomic_store(r1 + (size_t)tid * 4 + i, SENT64, __ATOMIC_RELAXED,
                       __HIP_MEMORY_SCOPE_AGENT);
  }
}

// ---- GEMM: C[8192][4096] = A[8192][K] * BT[4096][K]^T ---------------------
template <int NKS, int LAY>
__global__ __launch_bounds__(256) void k_gemm(
    const ushort_t* __restrict__ Af, const ushort_t* __restrict__ BT,
    ushort_t* __restrict__ C) {
  const int K = NKS * 16;
  const int xcd = blockIdx.x & 7, loc = blockIdx.x >> 3;
  const int wgM = xcd * 8 + (loc & 7);
  const int wgN = loc >> 3;
  const int tid = threadIdx.x;
  const int l = tid & 63;
  const int wv = tid >> 6;
  const int wvM = wv & 1, wvN = wv >> 1;

  __shared__ __align__(16) ushort_t Alds[4096];
  __shared__ __align__(16) ushort_t Blds[4096];

  const int m0 = wgM * 128, n0 = wgN * 128;
  f32x4 acc[4][4] = {};

  for (int k0 = 0; k0 < K; k0 += 32) {
    __syncthreads();
#pragma unroll
    for (int jj = 0; jj < 2; ++jj) {
      int c = jj * 256 + tid;
      int kc = c >> 7, r = c & 127;
      int R = m0 + r;
      int kcg = (k0 >> 3) + kc;
      const ushort_t* asrc =
          (LAY == 0) ? (Af + (size_t)R * 256 + kcg * 8)
                     : (Af + (size_t)(R >> 6) * 65536 + (R & 63) * 1024 + kcg * 8);
      gload_lds16(asrc, (ushort_t*)&Alds[(size_t)(jj * 256 + (tid & ~63)) * 8]);
      gload_lds16(BT + (size_t)(n0 + r) * K + k0 + kc * 8,
                  (ushort_t*)&Blds[(size_t)(jj * 256 + (tid & ~63)) * 8]);
    }
    __syncthreads();

    short8 af[4], bf[4];
#pragma unroll
    for (int mt = 0; mt < 4; ++mt)
      af[mt] = *(const short8*)&Alds[((l >> 4) * 128 + wvM * 64 + mt * 16 + (l & 15)) * 8];
#pragma unroll
    for (int nt = 0; nt < 4; ++nt)
      bf[nt] = *(const short8*)&Blds[((l >> 4) * 128 + wvN * 64 + nt * 16 + (l & 15)) * 8];
#pragma unroll
    for (int mt = 0; mt < 4; ++mt)
#pragma unroll
      for (int nt = 0; nt < 4; ++nt)
        acc[mt][nt] =
            __builtin_amdgcn_mfma_f32_16x16x32_bf16(af[mt], bf[nt], acc[mt][nt], 0, 0, 0);
  }

  const int rr0 = wgM * 128 + wvM * 64 + (l >> 4) * 4;
  const int cc0 = wgN * 128 + wvN * 64 + (l & 15);
#pragma unroll
  for (int mt = 0; mt < 4; ++mt)
#pragma unroll
    for (int nt = 0; nt < 4; ++nt)
#pragma unroll
      for (int r = 0; r < 4; ++r)
        C[(size_t)(rr0 + mt * 16 + r) * 4096 + cc0 + nt * 16] =
            f2b(acc[mt][nt][r]);
}

// ---- persistent LSTM layer, data-as-flag v2, <<<256,256>>> ----------------
// bid: chain = bid&3 (rows chain*16..+16), ws = bid>>2 (pc ws*64..+64).
// Wave kq = K-quarter; A polled via sentinel sc-loads (8 x 16B per lane).
template <int LAYER>
__global__ __launch_bounds__(256, 1) void k_pers(
    const ushort_t* __restrict__ Uf,    // frag order (k_convert_u)
    const ushort_t* __restrict__ XW,    // [8192][4096] bf16 row-major
    const float* __restrict__ bp,       // [4096] permuted bias
    const ushort_t* __restrict__ h0s,   // initial-h slot (valid data)
    const ushort_t* __restrict__ hall_r,// read slots base
    ushort_t* __restrict__ hall_w,      // write slots base
    float* __restrict__ c_st,           // [64][1024] f32
    float* __restrict__ outp,           // L1: d_out
    const float* __restrict__ gamma, const float* __restrict__ beta,
    const float* __restrict__ mean, const float* __restrict__ var) {
  const int bid = blockIdx.x;
  const int chain = bid & 3;
  const int ws = bid >> 2;              // 0..63
  const int tid = threadIdx.x;
  const int l = tid & 63;
  const int kq = tid >> 6;              // wave = K-quarter

  __shared__ __align__(16) ushort_t Ulds[4][32][512];  // 128 KB U slice
  __shared__ float zls[4][4][16][17];                  // 17 KB K-reduce
  __shared__ ushort_t hrel[16][16];                    // 512 B

  // ---- stage U slice (8192 x 16B) ----
  {
    const ushort_t* src = Uf + (size_t)ws * 65536;
    for (int i = tid; i < 8192; i += 256)
      *(short8*)((ushort_t*)Ulds + (size_t)i * 8) =
          *(const short8*)(src + (size_t)i * 8);
  }

  // ---- per-thread epilogue constants: one (row,j) each ----
  const int row_e = tid & 15, j_o = tid >> 4;    // j_o 0..15
  const int rowg = chain * 16 + row_e;
  const int j = ws * 16 + j_o;
  float creg = c_st[rowg * 1024 + j];
  const f32x4 bias_v = *(const f32x4*)(bp + ws * 64 + j_o * 4);
  float scl = 0.f, sft = 0.f;
  if (LAYER == 1) {
    float inv = rsqrtf(var[j] + 1e-3f);
    scl = inv * gamma[j];
    sft = beta[j] - mean[j] * scl;
  }
  const int rowA = chain * 16 + (l & 15);
  const int kg8 = (l >> 4) * 8;

  lgkm0_bar();   // Ulds visible

#pragma unroll 1
  for (int t = 0; t < 128; ++t) {
    const ushort_t* hin =
        (LAYER == 0) ? (hall_r + (size_t)t * 65536)
                     : ((t == 0) ? h0s : (hall_r + (size_t)(t - 1) * 65536));
    ushort_t* hout = hall_w + (size_t)(LAYER == 0 ? t + 1 : t) * 65536;

    // ---- XW for this step (cached; overlaps with poll) ----
    short4v xw = *(const short4v*)(
        XW + ((size_t)(t * 64 + rowg) << 12) + ws * 64 + j_o * 4);

    // ---- A: my K-quarter of my chain's rows ----
    const ushort_t* ab = hin + (size_t)rowA * 1024 + kq * 256 + kg8;
    short8 ar[8];
    if (t == 0) {
#pragma unroll
      for (int ksl = 0; ksl < 8; ++ksl)
        ar[ksl] = *(const short8*)(ab + ksl * 32);
    } else {
      for (;;) {
        LOADSC(ar[0], ab, 0);
        LOADSC(ar[1], ab, 64);
        LOADSC(ar[2], ab, 128);
        LOADSC(ar[3], ab, 192);
        LOADSC(ar[4], ab, 256);
        LOADSC(ar[5], ab, 320);
        LOADSC(ar[6], ab, 384);
        LOADSC(ar[7], ab, 448);
        asm volatile("s_waitcnt vmcnt(0)" ::: "memory");
        __builtin_amdgcn_sched_barrier(0);
        bool ok = true;
#pragma unroll
        for (int ksl = 0; ksl < 8; ++ksl) {
          union { short8 s; u64 q[2]; } ua;
          ua.s = ar[ksl];
          ok &= ((unsigned short)ua.q[0] != SENT16);
          ok &= ((unsigned short)ua.q[1] != SENT16);
        }
        if (__all(ok)) break;
        __builtin_amdgcn_s_sleep(2);
      }
    }

    // ---- 32 MFMAs: 4 nt-tiles x 8 ks (A reg, B LDS) ----
    f32x4 acc[4] = {};
#pragma unroll
    for (int ksl = 0; ksl < 8; ++ksl) {
      short8 a = ar[ksl];
#pragma unroll
      for (int nt = 0; nt < 4; ++nt) {
        short8 b = *(const short8*)&Ulds[nt][kq * 8 + ksl][l * 8];
        acc[nt] = __builtin_amdgcn_mfma_f32_16x16x32_bf16(a, b, acc[nt], 0, 0, 0);
      }
    }

    // ---- z partials to LDS (16x16 C layout: col=l&15, row=(l>>4)*4+r) ----
#pragma unroll
    for (int nt = 0; nt < 4; ++nt)
#pragma unroll
      for (int r = 0; r < 4; ++r)
        zls[kq][nt][(l >> 4) * 4 + r][l & 15] = acc[nt][r];
    lgkm0_bar();

    // ---- epilogue: thread owns (row_e, j_o) ----
    const int nte = j_o >> 2, cb = (j_o & 3) * 4;
    f32x4 z0 = *(const f32x4*)&zls[0][nte][row_e][cb];
    f32x4 z1 = *(const f32x4*)&zls[1][nte][row_e][cb];
    f32x4 z2 = *(const f32x4*)&zls[2][nte][row_e][cb];
    f32x4 z3 = *(const f32x4*)&zls[3][nte][row_e][cb];
    f32x4 zs = (z0 + z1) + (z2 + z3);
    float zi = zs[0] + b2f((ushort_t)xw[0]) + bias_v[0];
    float zf = zs[1] + b2f((ushort_t)xw[1]) + bias_v[1];
    float zg = zs[2] + b2f((ushort_t)xw[2]) + bias_v[2];
    float zo = zs[3] + b2f((ushort_t)xw[3]) + bias_v[3];
    float ii = fsigmoid(zi), ff = fsigmoid(zf), oo = fsigmoid(zo);
    float gg = ftanh(zg);
    creg = ff * creg + ii * gg;
    float hn = oo * ftanh(creg);
    hrel[row_e][j_o] = f2b(hn);
    lgkm0_bar();

    // ---- h out: threads 0..15 store 32B (2 x 16B sc), NO drain ----
    if (tid < 16) {
      short8 v0 = *(const short8*)&hrel[tid][0];
      short8 v1 = *(const short8*)&hrel[tid][8];
      ushort_t* dst = hout + (size_t)(chain * 16 + tid) * 1024 + ws * 16;
      store16_sc(dst, v0);
      store16_sc(dst + 8, v1);
    }

    // ---- fire-and-forget output stores (drained by next poll's vmcnt) ----
    if (LAYER == 1) {
      outp[((size_t)rowg * 128 + t) * 1024 + j] = hn * scl + sft;
      if (t == 127) {
        outp[8388608 + rowg * 1024 + j] = hn;
        outp[8454144 + rowg * 1024 + j] = creg;
      }
    } else if (t == 127) {
      c_st[rowg * 1024 + j] = creg;
    }
  }
}

extern "C" void kernel_launch(void* const* d_in, const int* in_sizes, int n_in,
                              void* d_out, int out_size, void* d_ws,
                              size_t ws_size, hipStream_t stream) {
  const int* tokens = (const int*)d_in[0];
  const float* h0 = (const float*)d_in[1];
  const float* c0 = (const float*)d_in[2];
  const float* emb = (const float*)d_in[3];
  const float* W0 = (const float*)d_in[4];
  const float* U0 = (const float*)d_in[5];
  const float* b0 = (const float*)d_in[6];
  const float* W1 = (const float*)d_in[7];
  const float* U1 = (const float*)d_in[8];
  const float* b1 = (const float*)d_in[9];
  const float* gammap = (const float*)d_in[10];
  const float* betap = (const float*)d_in[11];
  const float* mmean = (const float*)d_in[12];
  const float* mvar = (const float*)d_in[13];

  char* ws = (char*)d_ws;
  ushort_t* Uc0 = (ushort_t*)(ws + 0);             //  8 MB frag U0
  ushort_t* Uc1 = (ushort_t*)(ws + 8388608);       //  8 MB frag U1
  ushort_t* W0f = (ushort_t*)(ws + 16777216);      //  2 MB [pc][256]
  ushort_t* W1f = (ushort_t*)(ws + 18874368);      //  8 MB [pc][1024]
  float* bp0 = (float*)(ws + 27262976);            // 16 KB
  float* bp1 = (float*)(ws + 27279360);            // 16 KB
  ushort_t* Xef = (ushort_t*)(ws + 27295744);      //  4 MB [8192][256]
  ushort_t* XW = (ushort_t*)(ws + 31490048);       // 64 MB [8192][4096]
  ushort_t* hall0 = (ushort_t*)(ws + 98598912);    // 16.5 MB: 129 slots
  ushort_t* hall1 = (ushort_t*)(ws + 115507200);   // 16 MB: 128 slots
  float* c_st = (float*)(ws + 132284416);          // 256 KB

  k_convert_u<<<2048, 256, 0, stream>>>(U0, Uc0);
  k_convert_u<<<2048, 256, 0, stream>>>(U1, Uc1);
  k_convert<<<4096, 256, 0, stream>>>(W0, W0f, 8);
  k_convert<<<16384, 256, 0, stream>>>(W1, W1f, 10);
  k_bias<<<16, 256, 0, stream>>>(b0, b1, bp0, bp1);
  k_gather<<<8192, 256, 0, stream>>>(tokens, emb, Xef);
  k_init<<<256, 256, 0, stream>>>(h0, c0, hall0, c_st);
  k_nanfill<<<2048, 256, 0, stream>>>(hall0, hall1);

  float* outp = (float*)d_out;

  // ---- layer 0 (reads hall0[t], writes hall0[t+1]) ----
  k_gemm<16, 0><<<2048, 256, 0, stream>>>(Xef, W0f, XW);
  k_pers<0><<<256, 256, 0, stream>>>(Uc0, XW, bp0, nullptr, hall0, hall0,
                                     c_st, nullptr, nullptr, nullptr, nullptr,
                                     nullptr);

  // ---- layer 1 (GEMM A = hall0 slots 1..128; h init = hall0 slot 128) ----
  k_gemm<64, 1><<<2048, 256, 0, stream>>>(hall0 + 65536, W1f, XW);
  k_pers<1><<<256, 256, 0, stream>>>(Uc1, XW, bp1,
                                     hall0 + (size_t)128 * 65536, hall1, hall1,
                                     c_st, outp, gammap, betap, mmean, mvar);
}